// Round 2
// baseline (1424.129 us; speedup 1.0000x reference)
//
#include <hip/hip_runtime.h>
#include <cstdint>
#include <cstddef>

typedef _Float16 f16x8 __attribute__((ext_vector_type(8)));
typedef _Float16 f16x4 __attribute__((ext_vector_type(4)));
typedef float    f32x4 __attribute__((ext_vector_type(4)));

#define TFR  11
#define HID  1024
#define DQK  256
#define NBATCH 8192
#define MROWS (NBATCH*TFR)   /* 90112 */
#define NQK 512              /* Q cat K cols */

// ws layout (bytes). Total ~271 MB.
#define OFF_HF16   ((size_t)0)                       // [90112,1024] f16; becomes hmix after attn
#define OFF_QK     ((size_t)184549376)               // [90112,512] f16
#define OFF_WQK    ((size_t)276824064)               // [512,1024] f16
#define OFF_WO     ((size_t)277872640)               // [1024,1024] f16
#define OFF_WVT    ((size_t)279969792)               // [1024,1024] f16 (Wv^T)
#define OFF_WOV    ((size_t)282066944)               // [1024,1024] f16 (Wo@Wv)
#define OFF_BQK    ((size_t)284164096)               // [512] f32
#define OFF_BFUSED ((size_t)284166144)               // [1024] f32
#define OFF_TAB    ((size_t)284170240)               // [121] f32

static __device__ __forceinline__ void gl2lds16(const void* g, void* l) {
  __builtin_amdgcn_global_load_lds(
      (const __attribute__((address_space(1))) void*)g,
      (__attribute__((address_space(3))) void*)l, 16, 0, 0);
}

// ---------------------------------------------------------------------------
// h (f32) -> hf16. 45056 blocks x 256 threads x 8 elems.
// ---------------------------------------------------------------------------
__global__ __launch_bounds__(256)
void cvt_h(const float* __restrict__ h, _Float16* __restrict__ hf)
{
  const size_t i = ((size_t)blockIdx.x * 256 + threadIdx.x) * 8;
  f32x4 a = *(const f32x4*)&h[i];
  f32x4 b = *(const f32x4*)&h[i + 4];
  f16x8 o;
  o[0]=(_Float16)a[0]; o[1]=(_Float16)a[1]; o[2]=(_Float16)a[2]; o[3]=(_Float16)a[3];
  o[4]=(_Float16)b[0]; o[5]=(_Float16)b[1]; o[6]=(_Float16)b[2]; o[7]=(_Float16)b[3];
  *(f16x8*)&hf[i] = o;
}

// ---------------------------------------------------------------------------
// weight prep: Wqk cat+cvt, Wo cvt, Wv transpose+cvt, bqk, coulomb table.
// grid 1280 x 256 = 327680 indices.
// ---------------------------------------------------------------------------
__global__ __launch_bounds__(256)
void prep_w(const float* __restrict__ Wq, const float* __restrict__ Wk,
            const float* __restrict__ Wv, const float* __restrict__ Wo,
            const float* __restrict__ bq, const float* __restrict__ bk,
            const float* __restrict__ screen_d, const float* __restrict__ scale,
            _Float16* __restrict__ wqk, _Float16* __restrict__ wo,
            _Float16* __restrict__ wvt, float* __restrict__ bqk,
            float* __restrict__ tab)
{
  const int idx = blockIdx.x * 256 + threadIdx.x;
  if (idx < 65536) {                       // Wqk: [512,1024]
    const int n = idx >> 7, c = (idx & 127) * 8;
    const float* src = (n < 256) ? &Wq[(size_t)n * 1024 + c]
                                 : &Wk[(size_t)(n - 256) * 1024 + c];
    f32x4 a = *(const f32x4*)src, b = *(const f32x4*)(src + 4);
    f16x8 o;
    o[0]=(_Float16)a[0]; o[1]=(_Float16)a[1]; o[2]=(_Float16)a[2]; o[3]=(_Float16)a[3];
    o[4]=(_Float16)b[0]; o[5]=(_Float16)b[1]; o[6]=(_Float16)b[2]; o[7]=(_Float16)b[3];
    *(f16x8*)&wqk[(size_t)n * 1024 + c] = o;
  } else if (idx < 196608) {               // Wo cvt
    const size_t e = (size_t)(idx - 65536) * 8;
    f32x4 a = *(const f32x4*)&Wo[e], b = *(const f32x4*)&Wo[e + 4];
    f16x8 o;
    o[0]=(_Float16)a[0]; o[1]=(_Float16)a[1]; o[2]=(_Float16)a[2]; o[3]=(_Float16)a[3];
    o[4]=(_Float16)b[0]; o[5]=(_Float16)b[1]; o[6]=(_Float16)b[2]; o[7]=(_Float16)b[3];
    *(f16x8*)&wo[e] = o;
  } else if (idx < 327680) {               // WvT[n,k] = Wv[k,n]
    const int j = idx - 196608;
    const int n = j & 1023, kc = j >> 10;  // kc: 0..127
    f16x8 o;
#pragma unroll
    for (int e = 0; e < 8; ++e)
      o[e] = (_Float16)Wv[(size_t)(kc * 8 + e) * 1024 + n];
    *(f16x8*)&wvt[(size_t)n * 1024 + kc * 8] = o;
  }
  if (idx < 512) bqk[idx] = (idx < 256) ? bq[idx] : bk[idx - 256];
  if (idx < TFR * TFR) {
    const int i = idx / TFR, j = idx % TFR;
    const float r = fabsf((float)(i - j));
    float acc = 0.f, sign = 1.f;
    for (int k = 0; k < 3; ++k) {
      const float d = screen_d[k];
      acc += sign * rsqrtf(d * d + r * r + 1e-6f);
      sign = -sign;
    }
    tab[idx] = acc / (scale[0] + 1e-6f);
  }
}

// bfused[o] = sum_m Wo[o,m]*bv[m] + bo[o].  grid 1024 x 64 (one wave/row).
__global__ __launch_bounds__(64)
void bfused_k(const float* __restrict__ Wo, const float* __restrict__ bv,
              const float* __restrict__ bo, float* __restrict__ bf)
{
  const int o = blockIdx.x, l = threadIdx.x;
  float acc = 0.f;
  for (int m = l; m < 1024; m += 64) acc += Wo[(size_t)o * 1024 + m] * bv[m];
#pragma unroll
  for (int off = 32; off >= 1; off >>= 1) acc += __shfl_xor(acc, off);
  if (l == 0) bf[o] = acc + bo[o];
}

// ---------------------------------------------------------------------------
// f16 MFMA GEMM (m97 structure): out[m,n] = sum_k A[m,k]*B[n,k] (+bias[n]) (+res)
// A f16 [M,K] lda; B f16 [N,K]. MODE 0: f16 out. MODE 1: f32 out + f32 res.
// 128x128 tile, BK=32, 256 thr (2x2 waves of 64x64), 16x16x32 f16 MFMA.
// grid: x = N/128 (fast, reuses A tile in L2), y = M/128.
// ---------------------------------------------------------------------------
struct __align__(16) GemmSmem {
  union {
    struct { _Float16 A[128 * 32]; _Float16 B[128 * 32]; } st;  // 16 KB
    _Float16 E16[128 * 136];   // 34816 B  (MODE 0 epilogue)
    float    E32[64 * 132];    // 33792 B  (MODE 1 epilogue, 64-row halves)
  };
};

template <int MODE>
__global__ __launch_bounds__(256)
void gemm_f16(const _Float16* __restrict__ A, int lda,
              const _Float16* __restrict__ B,
              const float* __restrict__ bias,
              const float* __restrict__ res, int ldr,
              void* __restrict__ outv, int ldo, int K)
{
  __shared__ GemmSmem sm;
  const int t  = threadIdx.x;
  const int n0 = blockIdx.x * 128;
  const int m0 = blockIdx.y * 128;
  const int w  = t >> 6, l = t & 63;
  const int wm = (w & 1) * 64, wn = (w >> 1) * 64;
  const int lr = l & 15, lg = l >> 4;

  f32x4 acc[4][4] = {};

  const int qa = t, qb = t + 256;   // 16B chunk ids: row q>>2, sub-chunk q&3
  const _Float16* Arow0 = A + (size_t)(m0 + (qa >> 2)) * lda + (qa & 3) * 8;
  const _Float16* Arow1 = A + (size_t)(m0 + (qb >> 2)) * lda + (qb & 3) * 8;
  const _Float16* Brow0 = B + (size_t)(n0 + (qa >> 2)) * K + (qa & 3) * 8;
  const _Float16* Brow1 = B + (size_t)(n0 + (qb >> 2)) * K + (qb & 3) * 8;
  _Float16* ldsA0 = &sm.st.A[qa * 8];
  _Float16* ldsA1 = &sm.st.A[qb * 8];
  _Float16* ldsB0 = &sm.st.B[qa * 8];
  _Float16* ldsB1 = &sm.st.B[qb * 8];

  for (int kt = 0; kt < K; kt += 32) {
    gl2lds16(Arow0 + kt, ldsA0);
    gl2lds16(Arow1 + kt, ldsA1);
    gl2lds16(Brow0 + kt, ldsB0);
    gl2lds16(Brow1 + kt, ldsB1);
    __syncthreads();

    f16x8 af[4], bf[4];
#pragma unroll
    for (int mi = 0; mi < 4; ++mi)
      af[mi] = *(const f16x8*)&sm.st.A[(wm + mi * 16 + lr) * 32 + lg * 8];
#pragma unroll
    for (int ni = 0; ni < 4; ++ni)
      bf[ni] = *(const f16x8*)&sm.st.B[(wn + ni * 16 + lr) * 32 + lg * 8];
#pragma unroll
    for (int mi = 0; mi < 4; ++mi)
#pragma unroll
      for (int ni = 0; ni < 4; ++ni)
        acc[mi][ni] = __builtin_amdgcn_mfma_f32_16x16x32_f16(af[mi], bf[ni], acc[mi][ni], 0, 0, 0);
    __syncthreads();
  }

  if constexpr (MODE == 0) {
    _Float16* out = (_Float16*)outv;
    float bias4[4];
#pragma unroll
    for (int ni = 0; ni < 4; ++ni)
      bias4[ni] = bias ? bias[n0 + wn + ni * 16 + lr] : 0.0f;
#pragma unroll
    for (int mi = 0; mi < 4; ++mi)
#pragma unroll
      for (int ni = 0; ni < 4; ++ni) {
        const int row = wm + mi * 16 + lg * 4;   // C/D: col=lane&15, row=(lane>>4)*4+reg
        const int col = wn + ni * 16 + lr;
#pragma unroll
        for (int r = 0; r < 4; ++r)
          sm.E16[(row + r) * 136 + col] = (_Float16)(acc[mi][ni][r] + bias4[ni]);
      }
    __syncthreads();
#pragma unroll
    for (int i = 0; i < 8; ++i) {
      const int q = t + i * 256;               // row q>>4, col chunk q&15
      const int row = q >> 4, c = (q & 15) * 8;
      *(f16x8*)&out[(size_t)(m0 + row) * ldo + n0 + c] = *(const f16x8*)&sm.E16[row * 136 + c];
    }
  } else {
    float* out = (float*)outv;
#pragma unroll
    for (int p = 0; p < 2; ++p) {            // 64-row halves
      if (wm == p * 64) {
#pragma unroll
        for (int mi = 0; mi < 4; ++mi)
#pragma unroll
          for (int ni = 0; ni < 4; ++ni) {
            const int row = mi * 16 + lg * 4;
            const int col = wn + ni * 16 + lr;
#pragma unroll
            for (int r = 0; r < 4; ++r)
              sm.E32[(row + r) * 132 + col] = acc[mi][ni][r];
          }
      }
      __syncthreads();
#pragma unroll
      for (int i = 0; i < 8; ++i) {
        const int q = t + i * 256;           // 2048 f32x4 chunks: row q>>5, col (q&31)*4
        const int row = q >> 5, c = (q & 31) * 4;
        const int gr = m0 + p * 64 + row;
        f32x4 v = *(const f32x4*)&sm.E32[row * 132 + c];
        f32x4 bv4 = *(const f32x4*)&bias[n0 + c];
        f32x4 rv  = *(const f32x4*)&res[(size_t)gr * ldr + n0 + c];
#pragma unroll
        for (int e = 0; e < 4; ++e) v[e] += bv4[e] + rv[e];
        *(f32x4*)&out[(size_t)gr * ldo + n0 + c] = v;
      }
      __syncthreads();
    }
  }
}

// ---------------------------------------------------------------------------
// attention fold: per batch, scores = Q K^T/16 + bias, softmax, hmix = P @ h.
// hmix overwrites the batch's hf16 slab (block-local, safe).
// ---------------------------------------------------------------------------
__global__ __launch_bounds__(256)
void attn_fold(const _Float16* __restrict__ qk, _Float16* __restrict__ hf,
               const float* __restrict__ tab)
{
  __shared__ __align__(16) _Float16 sQK[TFR * NQK];   // 11264 B
  __shared__ __align__(16) _Float16 sH[TFR * HID];    // 22528 B
  __shared__ float sSc[TFR][12];
  __shared__ float sP[TFR][12];
  const int t = threadIdx.x;
  const size_t bq = (size_t)blockIdx.x * TFR * NQK;
  const size_t bh = (size_t)blockIdx.x * TFR * HID;

  for (int q = t; q < TFR * NQK / 8; q += 256)
    *(f16x8*)&sQK[q * 8] = *(const f16x8*)&qk[bq + (size_t)q * 8];
  for (int q = t; q < TFR * HID / 8; q += 256)
    *(f16x8*)&sH[q * 8] = *(const f16x8*)&hf[bh + (size_t)q * 8];
  __syncthreads();

  if (t < TFR * TFR) {
    const int i = t / TFR, j = t % TFR;
    float acc = 0.f;
    for (int c = 0; c < DQK; ++c)
      acc += (float)sQK[i * NQK + c] * (float)sQK[j * NQK + 256 + c];
    sSc[i][j] = acc * 0.0625f + tab[t];   // 1/sqrt(256)
  }
  __syncthreads();

  if (t < TFR) {
    float mx = sSc[t][0];
    for (int j = 1; j < TFR; ++j) mx = fmaxf(mx, sSc[t][j]);
    float e[TFR], sum = 0.f;
    for (int j = 0; j < TFR; ++j) { e[j] = __expf(sSc[t][j] - mx); sum += e[j]; }
    const float inv = 1.f / sum;
    for (int j = 0; j < TFR; ++j) sP[t][j] = e[j] * inv;
  }
  __syncthreads();

  const int c = t * 4;
#pragma unroll
  for (int i = 0; i < TFR; ++i) {
    float a0 = 0, a1 = 0, a2 = 0, a3 = 0;
#pragma unroll
    for (int j = 0; j < TFR; ++j) {
      const float p = sP[i][j];
      const _Float16* hj = &sH[j * HID + c];
      a0 += p * (float)hj[0]; a1 += p * (float)hj[1];
      a2 += p * (float)hj[2]; a3 += p * (float)hj[3];
    }
    f16x4 ov = { (_Float16)a0, (_Float16)a1, (_Float16)a2, (_Float16)a3 };
    *(f16x4*)&hf[bh + (size_t)i * HID + c] = ov;
  }
}

// ---------------------------------------------------------------------------
// LayerNorm over rows of 1024 f32, in-place.
// ---------------------------------------------------------------------------
__global__ __launch_bounds__(256)
void ln1024(float* __restrict__ x, const float* __restrict__ gamma,
            const float* __restrict__ beta)
{
  const int t = threadIdx.x;
  float* p = x + (size_t)blockIdx.x * HID;
  f32x4 v = *(const f32x4*)&p[t * 4];
  float s = v[0] + v[1] + v[2] + v[3];
  float s2 = v[0]*v[0] + v[1]*v[1] + v[2]*v[2] + v[3]*v[3];
#pragma unroll
  for (int off = 32; off >= 1; off >>= 1) {
    s  += __shfl_xor(s, off);
    s2 += __shfl_xor(s2, off);
  }
  __shared__ float red[8];
  const int w = t >> 6, l = t & 63;
  if (l == 0) { red[w] = s; red[w + 4] = s2; }
  __syncthreads();
  s  = red[0] + red[1] + red[2] + red[3];
  s2 = red[4] + red[5] + red[6] + red[7];
  const float mu  = s * (1.f / HID);
  const float var = s2 * (1.f / HID) - mu * mu;
  const float rs  = rsqrtf(var + 1e-5f);
  f32x4 g = *(const f32x4*)&gamma[t * 4];
  f32x4 b = *(const f32x4*)&beta[t * 4];
  f32x4 o;
#pragma unroll
  for (int e = 0; e < 4; ++e) o[e] = (v[e] - mu) * rs * g[e] + b[e];
  *(f32x4*)&p[t * 4] = o;
}

// ---------------------------------------------------------------------------
extern "C" void kernel_launch(void* const* d_in, const int* in_sizes, int n_in,
                              void* d_out, int out_size, void* d_ws, size_t ws_size,
                              hipStream_t stream)
{
  const float* h     = (const float*)d_in[0];
  const float* Wq    = (const float*)d_in[1];
  const float* bq    = (const float*)d_in[2];
  const float* Wk    = (const float*)d_in[3];
  const float* bk    = (const float*)d_in[4];
  const float* Wv    = (const float*)d_in[5];
  const float* bv    = (const float*)d_in[6];
  const float* Wo    = (const float*)d_in[7];
  const float* bo    = (const float*)d_in[8];
  const float* gamma = (const float*)d_in[9];
  const float* beta  = (const float*)d_in[10];
  const float* sd    = (const float*)d_in[11];
  const float* scal  = (const float*)d_in[12];
  float* out = (float*)d_out;

  char* w = (char*)d_ws;
  _Float16* hf16 = (_Float16*)(w + OFF_HF16);
  _Float16* qkf  = (_Float16*)(w + OFF_QK);
  _Float16* wqk  = (_Float16*)(w + OFF_WQK);
  _Float16* wo16 = (_Float16*)(w + OFF_WO);
  _Float16* wvt  = (_Float16*)(w + OFF_WVT);
  _Float16* wov  = (_Float16*)(w + OFF_WOV);
  float* bqk     = (float*)(w + OFF_BQK);
  float* bfused  = (float*)(w + OFF_BFUSED);
  float* tab     = (float*)(w + OFF_TAB);

  cvt_h<<<45056, 256, 0, stream>>>(h, hf16);
  prep_w<<<1280, 256, 0, stream>>>(Wq, Wk, Wv, Wo, bq, bk, sd, scal,
                                   wqk, wo16, wvt, bqk, tab);
  bfused_k<<<1024, 64, 0, stream>>>(Wo, bv, bo, bfused);

  // Wov = Wo @ Wv  (f16): out[o,hcol] = sum_k Wo[o,k] * WvT[hcol,k]
  gemm_f16<0><<<dim3(8, 8), 256, 0, stream>>>(wo16, 1024, wvt, nullptr,
                                              nullptr, 0, wov, 1024, 1024);
  // QK = h @ Wqk^T + bqk
  gemm_f16<0><<<dim3(4, 704), 256, 0, stream>>>(hf16, 1024, wqk, bqk,
                                                nullptr, 0, qkf, NQK, 1024);
  attn_fold<<<NBATCH, 256, 0, stream>>>(qkf, hf16, tab);

  // out = hmix @ Wov^T + bfused + h   (f32 out)
  gemm_f16<1><<<dim3(8, 704), 256, 0, stream>>>(hf16, 1024, wov, bfused,
                                                h, 1024, out, 1024, 1024);
  ln1024<<<MROWS, 256, 0, stream>>>(out, gamma, beta);
}